// Round 8
// baseline (467.515 us; speedup 1.0000x reference)
//
#include <hip/hip_runtime.h>

typedef __attribute__((ext_vector_type(8))) short bf16x8;   // 8 bf16 = 4 VGPRs
typedef __attribute__((ext_vector_type(4))) float f32x4;    // MFMA acc

constexpr int NB = 4, NL = 1024, NH = 8, NE = 64, NBH = NB * NH;

// Output layout (flat f32, return order: V, series, prior, sig)
constexpr size_t OFF_V      = 0;
constexpr size_t OFF_SERIES = (size_t)NB * NL * NH * NE;               // 2097152
constexpr size_t OFF_PRIOR  = OFF_SERIES + (size_t)NBH * NL * NL;      // 35651584
constexpr size_t OFF_SIG    = OFF_PRIOR  + (size_t)NBH * NL * NL;      // 69206016

constexpr size_t NV = (size_t)NB * NL * NH * NE;                       // 2097152
// ws layout (floats): vpart[2][NV], spart[2][NBH*NL]
constexpr size_t WS_SPART   = 2 * NV;
constexpr size_t WS_FLOATS  = WS_SPART + 2 * (size_t)NBH * NL;         // ~4.26M

// f32 -> bf16 round-to-nearest-even
__device__ __forceinline__ unsigned short f2bf(float x) {
  unsigned int u = __builtin_bit_cast(unsigned int, x);
  u = (u + 0x7FFFu + ((u >> 16) & 1u)) >> 16;
  return (unsigned short)u;
}

__device__ __forceinline__ f32x4 mfma16(bf16x8 a, bf16x8 b, f32x4 c) {
  return __builtin_amdgcn_mfma_f32_16x16x32_bf16(a, b, c, 0, 0, 0);
}

// ---------------------------------------------------------------------------
// Staging split into load (global->regs) / write (regs->LDS) so next tile's
// loads issue under the current tile's compute (T14). K/Q: [64][128B] bf16,
// XOR-swizzled (byte ^= (row&7)<<4). V: s-pair packed, stride 68 dwords.
// ---------------------------------------------------------------------------
__device__ __forceinline__ void loadT(const float* __restrict__ src, float4* r) {
  const int t = threadIdx.x;
  const int s = t >> 2, q = t & 3;
  const float4* rp = (const float4*)(src + (size_t)s * (NH * NE) + q * 16);
  r[0] = rp[0]; r[1] = rp[1]; r[2] = rp[2]; r[3] = rp[3];
}

__device__ __forceinline__ void writeT(const float4* v, unsigned short* lds) {
  const int t = threadIdx.x;
  const int s = t >> 2, q = t & 3;
  unsigned int u[8];
  u[0] = f2bf(v[0].x) | ((unsigned)f2bf(v[0].y) << 16);
  u[1] = f2bf(v[0].z) | ((unsigned)f2bf(v[0].w) << 16);
  u[2] = f2bf(v[1].x) | ((unsigned)f2bf(v[1].y) << 16);
  u[3] = f2bf(v[1].z) | ((unsigned)f2bf(v[1].w) << 16);
  u[4] = f2bf(v[2].x) | ((unsigned)f2bf(v[2].y) << 16);
  u[5] = f2bf(v[2].z) | ((unsigned)f2bf(v[2].w) << 16);
  u[6] = f2bf(v[3].x) | ((unsigned)f2bf(v[3].y) << 16);
  u[7] = f2bf(v[3].z) | ((unsigned)f2bf(v[3].w) << 16);
  const int sw = (s & 7) << 4;
  char* row = (char*)lds + s * 128;
  *(uint4*)(row + ((q * 32)      ^ sw)) = make_uint4(u[0], u[1], u[2], u[3]);
  *(uint4*)(row + ((q * 32 + 16) ^ sw)) = make_uint4(u[4], u[5], u[6], u[7]);
}

__device__ __forceinline__ void loadV(const float* __restrict__ src, float4* r) {
  const int t = threadIdx.x;
  const int sp = t >> 3, ec = t & 7;
  const float* r0 = src + (size_t)(2 * sp) * (NH * NE) + ec * 8;
  const float* r1 = r0 + NH * NE;
  r[0] = ((const float4*)r0)[0]; r[1] = ((const float4*)r0)[1];
  r[2] = ((const float4*)r1)[0]; r[3] = ((const float4*)r1)[1];
}

__device__ __forceinline__ void writeV(const float4* v, unsigned int* ldsv) {
  const int t = threadIdx.x;
  const int sp = t >> 3, ec = t & 7;
  unsigned int u[8];
  u[0] = f2bf(v[0].x) | ((unsigned)f2bf(v[2].x) << 16);
  u[1] = f2bf(v[0].y) | ((unsigned)f2bf(v[2].y) << 16);
  u[2] = f2bf(v[0].z) | ((unsigned)f2bf(v[2].z) << 16);
  u[3] = f2bf(v[0].w) | ((unsigned)f2bf(v[2].w) << 16);
  u[4] = f2bf(v[1].x) | ((unsigned)f2bf(v[3].x) << 16);
  u[5] = f2bf(v[1].y) | ((unsigned)f2bf(v[3].y) << 16);
  u[6] = f2bf(v[1].z) | ((unsigned)f2bf(v[3].z) << 16);
  u[7] = f2bf(v[1].w) | ((unsigned)f2bf(v[3].w) << 16);
  unsigned int* p = ldsv + sp * 68 + ec * 8;
  *(uint4*)(p)     = make_uint4(u[0], u[1], u[2], u[3]);
  *(uint4*)(p + 4) = make_uint4(u[4], u[5], u[6], u[7]);
}

__device__ __forceinline__ void stageQ(const float* __restrict__ src,
                                       unsigned short* lds) {
  float4 r[4];
  loadT(src, r);
  writeT(r, lds);
}

__device__ __forceinline__ bf16x8 readAB(const unsigned short* lds, int row,
                                         int bytecol) {
  const char* p = (const char*)lds + row * 128 + (bytecol ^ ((row & 7) << 4));
  return *(const bf16x8*)p;
}

// ---------------------------------------------------------------------------
// Fused attention, single pass, optional s-parity split (SPLIT=1: grid 1024,
// block (p,bh,w) does tiles st ≡ p (mod 2); 4 blocks/CU for 2x latency
// hiding; partial sums/V go to ws, combined by vreduce_norm).
// SPLIT=0 fallback = proven round-7 structure (grid 512, V normalized here).
// Per-CU balance: CU c holds parities {0,1} x w in {15-q, q}: 17 tiles exact.
// Fixed -20 exp shift replaces the softmax max pass (|attn| <~ 6).
// ---------------------------------------------------------------------------
template<bool SPLIT>
__global__ __launch_bounds__(256, 4)
void attn_kernel(const float* __restrict__ Qp, const float* __restrict__ Kp,
                 const float* __restrict__ Vp, float* __restrict__ ws,
                 float* __restrict__ out) {
  const int blk = blockIdx.x;
  const int bh = blk & 31;
  const int g6 = blk >> 5;
  const int p  = SPLIT ? (g6 >> 4) : 0;
  const int g5 = g6 & 15;
  const int w  = (g5 < 8) ? (15 - g5) : (g5 - 8);    // heavy-first pairing
  const int b = bh >> 3, h = bh & 7;
  const int start = SPLIT ? p : 0;
  const int step  = SPLIT ? 2 : 1;

  __shared__ unsigned short ldsQ[64 * 64];
  __shared__ unsigned short ldsK[64 * 64];
  __shared__ unsigned int   ldsV[32 * 68];
  __shared__ unsigned short ldsP[4][16 * 72];        // 144B stride, b128-aligned

  const int tid  = threadIdx.x;
  const int lane = tid & 63;
  const int wv   = tid >> 6;
  const int g    = lane >> 4;
  const int e0   = lane & 15;

  const size_t rowstride = NH * NE;                  // 512 floats
  const float* Qbase = Qp + ((size_t)(b * NL + w * 64) * NH + h) * NE;
  const float* Kbase = Kp + ((size_t)(b * NL) * NH + h) * NE;
  const float* Vbase = Vp + ((size_t)(b * NL) * NH + h) * NE;

  stageQ(Qbase, ldsQ);
  __syncthreads();

  const bf16x8 aq0 = readAB(ldsQ, wv * 16 + e0, g * 16);
  const bf16x8 aq1 = readAB(ldsQ, wv * 16 + e0, g * 16 + 64);

  const float scale = 0.125f;                        // 1/sqrt(64)
  const int r_glob0 = w * 64 + wv * 16 + g * 4;      // + j
  float rsum[4] = {0.f, 0.f, 0.f, 0.f};

  f32x4 acc_o[4];
#pragma unroll
  for (int i = 0; i < 4; ++i) acc_o[i] = f32x4{0.f, 0.f, 0.f, 0.f};

  unsigned short* ldsPw = ldsP[wv];
  float* __restrict__ series = out + OFF_SERIES + (size_t)bh * NL * NL;

  float4 kreg[4], vreg[4];
  if (start <= w) {                                  // tile-0 prefetch
    loadT(Kbase + (size_t)(start * 64) * rowstride, kreg);
    loadV(Vbase + (size_t)(start * 64) * rowstride, vreg);
  }

  for (int st = start; st <= w; st += step) {
    __syncthreads();                                 // prev tile readers done
    writeT(kreg, ldsK);                              // vmcnt wait lands here
    writeV(vreg, ldsV);
    __syncthreads();                                 // tile ready
    if (st + step <= w) {                            // next tile's loads hide
      loadT(Kbase + (size_t)((st + step) * 64) * rowstride, kreg);
      loadV(Vbase + (size_t)((st + step) * 64) * rowstride, vreg);
    }
#pragma unroll
    for (int ct = 0; ct < 4; ++ct) {
      f32x4 acc = {0.f, 0.f, 0.f, 0.f};
      bf16x8 bk0 = readAB(ldsK, ct * 16 + e0, g * 16);
      bf16x8 bk1 = readAB(ldsK, ct * 16 + e0, g * 16 + 64);
      acc = mfma16(aq0, bk0, acc);
      acc = mfma16(aq1, bk1, acc);
      const int s_g = st * 64 + ct * 16 + e0;
#pragma unroll
      for (int j = 0; j < 4; ++j) {
        float e = __expf(acc[j] * scale - 20.0f);
        if (s_g > r_glob0 + j) e = 0.f;              // causal mask
        rsum[j] += e;
        // unnormalized; D-layout store = 64B contiguous segments
        series[(size_t)(r_glob0 + j) * NL + s_g] = e;
        ldsPw[(g * 4 + j) * 72 + ct * 16 + e0] = f2bf(e);
      }
    }
    __builtin_amdgcn_s_setprio(1);
#pragma unroll
    for (int sh = 0; sh < 2; ++sh) {
      const char* pp = (const char*)ldsPw + e0 * 144 + sh * 64 + g * 16;
      const bf16x8 ap = *(const bf16x8*)pp;
#pragma unroll
      for (int ce = 0; ce < 4; ++ce) {
        const unsigned int* vp = ldsV + (sh * 16 + g * 4) * 68 + ce * 16 + e0;
        uint4 vw = make_uint4(vp[0], vp[68], vp[136], vp[204]);
        const bf16x8 bv = __builtin_bit_cast(bf16x8, vw);
        acc_o[ce] = mfma16(ap, bv, acc_o[ce]);
      }
    }
    __builtin_amdgcn_s_setprio(0);
  }

  // ---- epilogue ----
  float rred[4];
#pragma unroll
  for (int j = 0; j < 4; ++j) {                      // reduce 16-lane group
    float v = rsum[j];                               // sharing D rows
    v += __shfl_xor(v, 1);
    v += __shfl_xor(v, 2);
    v += __shfl_xor(v, 4);
    v += __shfl_xor(v, 8);
    rred[j] = v;
  }

  if (SPLIT) {
    float* spart = ws + WS_SPART + (size_t)p * (NBH * NL);
    if (e0 == 0) {
#pragma unroll
      for (int j = 0; j < 4; ++j) spart[(size_t)bh * NL + r_glob0 + j] = rred[j];
    }
    float* vpart = ws + (size_t)p * NV;
#pragma unroll
    for (int ce = 0; ce < 4; ++ce) {
#pragma unroll
      for (int j = 0; j < 4; ++j) {
        vpart[((size_t)(b * NL + r_glob0 + j) * NH + h) * NE + ce * 16 + e0] =
            acc_o[ce][j];
      }
    }
  } else {
    // fallback: normalize V here; write spart0 = sum, spart1 = 0
    float* spart0 = ws + WS_SPART;
    float* spart1 = ws + WS_SPART + (size_t)(NBH * NL);
    if (e0 == 0) {
#pragma unroll
      for (int j = 0; j < 4; ++j) {
        spart0[(size_t)bh * NL + r_glob0 + j] = rred[j];
        spart1[(size_t)bh * NL + r_glob0 + j] = 0.f;
      }
    }
    float* __restrict__ vout = out + OFF_V;
#pragma unroll
    for (int ce = 0; ce < 4; ++ce) {
#pragma unroll
      for (int j = 0; j < 4; ++j) {
        vout[((size_t)(b * NL + r_glob0 + j) * NH + h) * NE + ce * 16 + e0] =
            acc_o[ce][j] / rred[j];
      }
    }
  }
}

// ---------------------------------------------------------------------------
// vreduce_norm (SPLIT path): V = (v0+v1) / (s0+s1). 16MB read, 8MB write.
// ---------------------------------------------------------------------------
__global__ __launch_bounds__(256)
void vreduce_norm_kernel(const float* __restrict__ ws, float* __restrict__ out) {
  const size_t idx = (size_t)blockIdx.x * 256 + threadIdx.x;   // float4 index
  const size_t n4 = NV / 4;
  const float4* p0 = (const float4*)ws;
  const float4* p1 = p0 + n4;
  const size_t flat = idx * 4;
  const size_t rh   = flat / NE;                     // (b*NL + r)*NH + h
  const size_t h    = rh % NH;
  const size_t br   = rh / NH;                       // b*NL + r
  const size_t r    = br % NL;
  const size_t b    = br / NL;
  const float* spart = ws + WS_SPART;
  const size_t so = (b * NH + h) * NL + r;
  const float inv = 1.0f / (spart[so] + spart[so + NBH * NL]);
  float4 a = p0[idx], c = p1[idx];
  float4 o;
  o.x = (a.x + c.x) * inv;
  o.y = (a.y + c.y) * inv;
  o.z = (a.z + c.z) * inv;
  o.w = (a.w + c.w) * inv;
  ((float4*)(out + OFF_V))[idx] = o;
}

// ---------------------------------------------------------------------------
// prior + sig + series zeros/normalization. rinv = 1/(spart0+spart1).
// Band-limit: sigma = 3^sg-1 <= 2.0002, so for |l-s| >= 30 the reference's
// own f32 exp underflows to exactly 0.0f; skip exp when |l-sb| > 135 (chunk
// conservatively inside that bound) and write zeros -- bit-exact safe.
// ---------------------------------------------------------------------------
__global__ __launch_bounds__(256)
void prior_norm_kernel(const float* __restrict__ sigma,
                       const float* __restrict__ ws, float* __restrict__ out) {
  const float inv_sqrt_2pi = 0.39894228040143267f;
  const float ln3 = 1.0986122886681098f;
  float4* __restrict__ prior4  = (float4*)(out + OFF_PRIOR);
  float4* __restrict__ sig4    = (float4*)(out + OFF_SIG);
  float4* __restrict__ series4 = (float4*)(out + OFF_SERIES);

  const int tid  = threadIdx.x;
  const int lane = tid & 63;
  const int rowIdx = blockIdx.x * 4 + (tid >> 6);   // bh*1024 + l
  const int l  = rowIdx & 1023;
  const int bh = rowIdx >> 10;
  const int b  = bh >> 3, h = bh & 7;

  const float x    = sigma[((size_t)b * NL + l) * NH + h];
  const float sg   = 1.0f / (1.0f + __expf(-5.0f * x)) + 1e-5f;
  const float sigv = __expf(sg * ln3) - 1.0f;        // 3^sg - 1
  const float coef = inv_sqrt_2pi / sigv;
  const float inv2 = -0.5f / (sigv * sigv);
  const float* spart = ws + WS_SPART;
  const float rinv = 1.0f / (spart[rowIdx] + spart[rowIdx + NBH * NL]);

  const size_t rbase = (size_t)rowIdx * (NL / 4);
  const int rbe4 = ((l & ~63) + 64) >> 2;            // row-block end in chunks
  const float4 zero4 = make_float4(0.f, 0.f, 0.f, 0.f);
  const float4 sv = make_float4(sigv, sigv, sigv, sigv);

#pragma unroll
  for (int k = 0; k < 4; ++k) {
    const int c  = lane + k * 64;
    const int sb = c * 4;
    float4 pr = zero4;
    const int d = l - sb;
    if (d <= 135 && d >= -135) {                     // in Gaussian band
      const int d0 = d, d1 = d - 1, d2 = d - 2, d3 = d - 3;
      pr.x = coef * __expf((float)(d0 * d0) * inv2);
      pr.y = coef * __expf((float)(d1 * d1) * inv2);
      pr.z = coef * __expf((float)(d2 * d2) * inv2);
      pr.w = coef * __expf((float)(d3 * d3) * inv2);
    }
    prior4[rbase + c] = pr;
    sig4[rbase + c]   = sv;
    if (c >= rbe4) {
      series4[rbase + c] = zero4;                    // beyond causal block
    } else {
      float4 v = series4[rbase + c];                 // unnormalized from attn
      v.x *= rinv; v.y *= rinv; v.z *= rinv; v.w *= rinv;
      series4[rbase + c] = v;
    }
  }
}

// ---------------------------------------------------------------------------
extern "C" void kernel_launch(void* const* d_in, const int* in_sizes, int n_in,
                              void* d_out, int out_size, void* d_ws, size_t ws_size,
                              hipStream_t stream) {
  const float* Qp = (const float*)d_in[0];
  const float* Kp = (const float*)d_in[1];
  const float* Vp = (const float*)d_in[2];
  const float* Sg = (const float*)d_in[3];
  float* out = (float*)d_out;
  float* ws  = (float*)d_ws;

  if (ws_size >= WS_FLOATS * sizeof(float)) {
    attn_kernel<true><<<dim3(1024), dim3(256), 0, stream>>>(Qp, Kp, Vp, ws, out);
    vreduce_norm_kernel<<<dim3(NV / 4 / 256), dim3(256), 0, stream>>>(ws, out);
  } else {
    attn_kernel<false><<<dim3(512), dim3(256), 0, stream>>>(Qp, Kp, Vp, ws, out);
  }
  prior_norm_kernel<<<dim3(NBH * NL / 4), dim3(256), 0, stream>>>(Sg, ws, out);
}